// Round 8
// baseline (156.903 us; speedup 1.0000x reference)
//
#include <hip/hip_runtime.h>

#define CC 64
#define LL 1024
#define LOG2E 1.44269504f

typedef unsigned short u16;
typedef unsigned int u32;
typedef __attribute__((ext_vector_type(8))) short short8;
typedef __attribute__((ext_vector_type(4))) float floatx4;

// RN ties-away float->bf16 (2 VALU ops)
static __device__ __forceinline__ u16 f2b(float f) {
  return (u16)((__float_as_uint(f) + 0x8000u) >> 16);
}
static __device__ __forceinline__ u32 pk2(float a, float b) {
  return ((__float_as_uint(a) + 0x8000u) >> 16) |
         ((__float_as_uint(b) + 0x8000u) & 0xffff0000u);
}
// 1-op truncating pack: low16 <- hi16(a), high16 <- hi16(b)  (v_perm_b32)
static __device__ __forceinline__ u32 pk2t(float a, float b) {
  return __builtin_amdgcn_perm(__float_as_uint(b), __float_as_uint(a), 0x07060302u);
}
static __device__ __forceinline__ short8 mk8(u32 a, u32 b, u32 c, u32 d) {
  union { u32 u[4]; short8 s; } t;
  t.u[0] = a; t.u[1] = b; t.u[2] = c; t.u[3] = d;
  return t.s;
}

// ---------------- Phase 0: one-time W -> bf16 (+log2e fold on Wq), biases ----
// whi layout: [3][64 o][64 c] bf16 unpadded; L2-resident for qkv.
__global__ __launch_bounds__(256) void w_prep(
    const float* __restrict__ Wq, const float* __restrict__ bq,
    const float* __restrict__ Wk, const float* __restrict__ bk,
    const float* __restrict__ Wv, const float* __restrict__ bv,
    u16* __restrict__ whi, float* __restrict__ bsc)
{
  const int idx = blockIdx.x * 256 + threadIdx.x;   // grid 48 -> 12288
  const int m = idx >> 12;
  const float* W = (m == 0) ? Wq : (m == 1) ? Wk : Wv;
  const float w = W[idx & 4095] * ((m == 0) ? LOG2E : 1.0f);
  whi[idx] = f2b(w);
  if (blockIdx.x == 0 && threadIdx.x < 192)
    bsc[threadIdx.x] = (threadIdx.x < 64) ? bq[threadIdx.x] * LOG2E
                     : (threadIdx.x < 128) ? bk[threadIdx.x - 64] : bv[threadIdx.x - 128];
}

// ---------------- Phase 1: QKV projection, DIRECT-x --------------------------
// grid 1024 = 64 bt (XCD-pinned) x 16 l-chunks of 64. Direct global x loads
// (fully-used 64B sectors), no staging LDS. kT is now stored with rows
// SIGMA-PERMUTED within each 32-row group: true j = q*8 + t*4 + r stored at
// row t*16 + q*4 + r. This makes the attn S^T output registers across a
// stored-tile pair exactly the K=32 PV A-fragment (the round-2 LDS trick,
// moved into the global layout so attn can stream K straight from L2).
__global__ __launch_bounds__(256) void qkv_kernel(
    const float* __restrict__ x,
    const u16* __restrict__ whi, const float* __restrict__ bsc,
    u16* __restrict__ qT, u16* __restrict__ kT, u16* __restrict__ vO)
{
  __shared__ __align__(16) u16 tbuf_s[4 * 16 * 72];  // per-wave q/k transpose buf

  const int tid  = threadIdx.x;
  const int wave = tid >> 6;
  const int lane = tid & 63;
  const int l16  = lane & 15;
  const int quad = lane >> 4;

  const int bt = blockIdx.x & 63;                  // XCD pin matches attn consumer
  const int l0 = (blockIdx.x >> 6) << 6;           // 64 l's per block
  const int l  = l0 + wave * 16 + l16;             // this thread's l

  // direct x loads: 16 independent f32 scalars (c = quad*8+e and +32)
  const float* xb = x + (size_t)bt * CC * LL + l;
  float xv0[8], xv1[8];
  #pragma unroll
  for (int e = 0; e < 8; ++e) {
    xv0[e] = xb[(size_t)(quad * 8 + e) * LL];
    xv1[e] = xb[(size_t)(quad * 8 + 32 + e) * LL];
  }
  const short8 xh0 = mk8(pk2(xv0[0], xv0[1]), pk2(xv0[2], xv0[3]),
                         pk2(xv0[4], xv0[5]), pk2(xv0[6], xv0[7]));
  const short8 xh1 = mk8(pk2(xv1[0], xv1[1]), pk2(xv1[2], xv1[3]),
                         pk2(xv1[4], xv1[5]), pk2(xv1[6], xv1[7]));

  u16* tb = tbuf_s + wave * 1152;

  #pragma unroll
  for (int ot = 0; ot < 12; ++ot) {
    const int m = ot >> 2;
    // unpadded whi: fragment rows 128B, tile read 2KB contiguous (L2-hit)
    const int off = (m << 12) + (((ot & 3) * 16 + l16) << 6) + quad * 8;
    const short8 ah0 = *(const short8*)(whi + off);
    const short8 ah1 = *(const short8*)(whi + off + 32);

    floatx4 acc = (floatx4){0.f, 0.f, 0.f, 0.f};
    acc = __builtin_amdgcn_mfma_f32_16x16x32_bf16(ah0, xh0, acc, 0, 0, 0);
    acc = __builtin_amdgcn_mfma_f32_16x16x32_bf16(ah1, xh1, acc, 0, 0, 0);

    const float4 bb = *(const float4*)(bsc + ot * 16 + quad * 4);  // broadcast
    float ov[4];
    ov[0] = acc[0] + bb.x; ov[1] = acc[1] + bb.y;
    ov[2] = acc[2] + bb.z; ov[3] = acc[3] + bb.w;

    if (ot < 8) {
      // D lane holds (o = quad*4+r, l = l16); write transposed [l][o]
      uint2 pv;
      pv.x = pk2(ov[0], ov[1]);
      pv.y = pk2(ov[2], ov[3]);
      *(uint2*)(tb + l16 * 72 + (ot & 3) * 16 + quad * 4) = pv;
      if ((ot & 3) == 3) {
        asm volatile("" ::: "memory");
        const int rr = lane >> 3;
        const int c8 = (lane & 7) * 8;
        if (ot < 4) {
          u16* gdst = qT + ((size_t)(bt * LL + l0 + wave * 16)) * CC;
          #pragma unroll
          for (int s2 = 0; s2 < 2; ++s2) {
            const int row = s2 * 8 + rr;
            uint4 val = *(const uint4*)(tb + row * 72 + c8);
            *(uint4*)(gdst + row * CC + c8) = val;   // 128B-contiguous rows
          }
        } else {
          // kT sigma-store: within-32 true j = (wave&1)*16 + s2*8 + rr
          //   fields q=(j>>3), t=(j>>2)&1, r=j&3 -> stored row t*16+q*4+r
          u16* gdst = kT + ((size_t)(bt * LL + l0 + (wave >> 1) * 32)) * CC;
          #pragma unroll
          for (int s2 = 0; s2 < 2; ++s2) {
            const int row = s2 * 8 + rr;                      // tbuf row (true)
            const int q2 = (wave & 1) * 2 + s2;               // j>>3
            const int srow = ((rr >> 2) << 4) + (q2 << 2) + (rr & 3);
            uint4 val = *(const uint4*)(tb + row * 72 + c8);
            *(uint4*)(gdst + srow * CC + c8) = val;  // full 128B rows, reordered
          }
        }
        asm volatile("" ::: "memory");
      }
    } else {
      const int ob = (ot - 8) * 16 + quad * 4;
      u16* vdst = vO + ((size_t)(bt * CC + ob)) * LL + l0 + wave * 16 + l16;
      #pragma unroll
      for (int r = 0; r < 4; ++r)
        vdst[(size_t)r * LL] = f2b(ov[r]);
    }
  }
}

// ---------------- Phase 2: flash attention, DIRECT-L2 streaming --------------
// grid 2048 = 64 bt (XCD-pinned: blk%8 == bt%8) x 32 chunks of 32 i; ONE
// 64-lane wave per block owning 32 i rows. NO LDS staging, NO barriers in
// the 16-iteration j-loop: K/V fragments are loaded straight from the
// XCD-pinned L2 (per-XCD working set 8 bt x 384KB = 3MB < 4MB L2).
//   - K A-frags: kT rows are sigma-permuted (see qkv) so the S^T output
//     regs across a stored-tile pair ARE the K=32 PV A-fragment: P never
//     leaves registers, no shuffles.
//   - V B-frags: plain vO[c][l], 16B/lane contiguous -> full 64B sectors.
// L2 read volume: 2048 waves x 16 iters x 16KB = 0.54GB -> ~16us floor at
// the per-XCD L2 ceiling; latency hidden by 16 indep loads/iter + no syncs.
__global__ __launch_bounds__(64) void attn_kernel(
    const u16* __restrict__ qT, const u16* __restrict__ kT,
    const u16* __restrict__ vB, float* __restrict__ out)
{
  __shared__ __align__(16) float of_s[1280];   // 5KB per-wave epilogue transpose
  const int lane = threadIdx.x;
  const int l16  = lane & 15;
  const int quad = lane >> 4;

  const int bt    = blockIdx.x & 63;
  const int chunk = blockIdx.x >> 6;          // 0..31
  const int i0    = chunk << 5;               // 32 i rows per wave

  const u16* kbase = kT + (size_t)bt * LL * CC;
  const u16* vbase = vB + (size_t)bt * CC * LL;

  short8 qf[2][2];
  #pragma unroll
  for (int s = 0; s < 2; ++s) {
    const u16* qr = qT + (size_t)bt * LL * CC + (size_t)(i0 + s * 16 + l16) * CC + quad * 8;
    qf[s][0] = *(const short8*)(qr);
    qf[s][1] = *(const short8*)(qr + 32);
  }

  floatx4 O[2][4];
  #pragma unroll
  for (int s = 0; s < 2; ++s)
    #pragma unroll
    for (int cf = 0; cf < 4; ++cf)
      O[s][cf] = (floatx4){0.f, 0.f, 0.f, 0.f};
  float ls[2] = {0.f, 0.f};

  for (int it = 0; it < 16; ++it) {
    const int jb = it << 6;

    // V fragments first: independent loads, deepest latency slack.
    // vf[p][cf] covers true j-window [jb+p*32, jb+p*32+32), 16B/lane.
    uint4 vf[2][4];
    #pragma unroll
    for (int p = 0; p < 2; ++p)
      #pragma unroll
      for (int cf = 0; cf < 4; ++cf)
        vf[p][cf] = *(const uint4*)(vbase + (size_t)(cf * 16 + l16) * LL
                                    + jb + p * 32 + quad * 8);

    // S^T: D[j_stored][i] over 4 stored 16-row tiles (sigma order)
    floatx4 S[2][4];
    #pragma unroll
    for (int jt = 0; jt < 4; ++jt) {
      const u16* ka = kbase + (size_t)(jb + jt * 16 + l16) * CC + quad * 8;
      const short8 a0 = *(const short8*)(ka);
      const short8 a1 = *(const short8*)(ka + 32);
      #pragma unroll
      for (int s = 0; s < 2; ++s) {
        floatx4 acc = (floatx4){0.f, 0.f, 0.f, 0.f};
        acc = __builtin_amdgcn_mfma_f32_16x16x32_bf16(a0, qf[s][0], acc, 0, 0, 0);
        acc = __builtin_amdgcn_mfma_f32_16x16x32_bf16(a1, qf[s][1], acc, 0, 0, 0);
        S[s][jt] = acc;
      }
    }

    // exp2 + partial sums + in-register bf16 pack
    uint2 pp[2][4];
    #pragma unroll
    for (int s = 0; s < 2; ++s)
      #pragma unroll
      for (int jt = 0; jt < 4; ++jt) {
        const float e0 = __builtin_amdgcn_exp2f(S[s][jt][0]);
        const float e1 = __builtin_amdgcn_exp2f(S[s][jt][1]);
        const float e2 = __builtin_amdgcn_exp2f(S[s][jt][2]);
        const float e3 = __builtin_amdgcn_exp2f(S[s][jt][3]);
        ls[s] += (e0 + e1) + (e2 + e3);
        pp[s][jt].x = pk2t(e0, e1);
        pp[s][jt].y = pk2t(e2, e3);
      }

    // O += P * V, K=32 per stored-tile pair (sigma makes pa lane-exact)
    #pragma unroll
    for (int s = 0; s < 2; ++s) {
      const short8 pa0 = mk8(pp[s][0].x, pp[s][0].y, pp[s][1].x, pp[s][1].y);
      const short8 pa1 = mk8(pp[s][2].x, pp[s][2].y, pp[s][3].x, pp[s][3].y);
      #pragma unroll
      for (int cf = 0; cf < 4; ++cf) {
        const short8 vb0 = mk8(vf[0][cf].x, vf[0][cf].y, vf[0][cf].z, vf[0][cf].w);
        const short8 vb1 = mk8(vf[1][cf].x, vf[1][cf].y, vf[1][cf].z, vf[1][cf].w);
        O[s][cf] = __builtin_amdgcn_mfma_f32_16x16x32_bf16(pa0, vb0, O[s][cf], 0, 0, 0);
        O[s][cf] = __builtin_amdgcn_mfma_f32_16x16x32_bf16(pa1, vb1, O[s][cf], 0, 0, 0);
      }
    }
  }

  #pragma unroll
  for (int s = 0; s < 2; ++s) {
    ls[s] += __shfl_xor(ls[s], 16, 64);
    ls[s] += __shfl_xor(ls[s], 32, 64);
  }

  // epilogue: scale by 1/lsum, transpose through LDS (single wave: no barrier,
  // compiler inserts lgkm waits; asm clobbers order the ds ops)
  #pragma unroll
  for (int s = 0; s < 2; ++s) {
    #pragma unroll
    for (int r = 0; r < 4; ++r) {
      const float rl = __builtin_amdgcn_rcpf(__shfl(ls[s], quad * 4 + r, 64));
      #pragma unroll
      for (int cf = 0; cf < 4; ++cf)
        O[s][cf][r] *= rl;
    }
    asm volatile("" ::: "memory");
    #pragma unroll
    for (int cf = 0; cf < 4; ++cf)
      #pragma unroll
      for (int r = 0; r < 4; ++r)
        of_s[(cf * 16 + l16) * 20 + quad * 4 + r] = O[s][cf][r];
    asm volatile("" ::: "memory");
    {
      float* ob = out + (size_t)bt * CC * LL + i0 + s * 16;
      #pragma unroll
      for (int rr = 0; rr < 4; ++rr) {
        const int c = rr * 16 + l16;
        float4 val = *(const float4*)(of_s + c * 20 + quad * 4);
        *(float4*)(ob + (size_t)c * LL + quad * 4) = val;
      }
    }
    asm volatile("" ::: "memory");
  }
}

extern "C" void kernel_launch(void* const* d_in, const int* in_sizes, int n_in,
                              void* d_out, int out_size, void* d_ws, size_t ws_size,
                              hipStream_t stream) {
  const float* x  = (const float*)d_in[0];
  const float* Wq = (const float*)d_in[1];
  const float* bq = (const float*)d_in[2];
  const float* Wk = (const float*)d_in[3];
  const float* bk = (const float*)d_in[4];
  const float* Wv = (const float*)d_in[5];
  const float* bv = (const float*)d_in[6];
  float* out = (float*)d_out;

  u16* qTp = (u16*)d_ws;                          // 8 MB
  u16* kTp = qTp + (size_t)64 * LL * CC;          // 8 MB (sigma row order)
  u16* vp  = kTp + (size_t)64 * LL * CC;          // 8 MB
  u16* whi = vp  + (size_t)64 * LL * CC;          // 24 KB
  float* bsc = (float*)(whi + 3 * 64 * 64);       // 768 B

  w_prep<<<48, 256, 0, stream>>>(Wq, bq, Wk, bk, Wv, bv, whi, bsc);
  qkv_kernel<<<1024, 256, 0, stream>>>(x, whi, bsc, qTp, kTp, vp);
  attn_kernel<<<2048, 64, 0, stream>>>(qTp, kTp, vp, out);
}

// Round 9
// 129.113 us; speedup vs baseline: 1.2152x; 1.2152x over previous
//
#include <hip/hip_runtime.h>

#define CC 64
#define LL 1024
#define LOG2E 1.44269504f

typedef unsigned short u16;
typedef unsigned int u32;
typedef __attribute__((ext_vector_type(8))) short short8;
typedef __attribute__((ext_vector_type(4))) float floatx4;

// RN ties-away float->bf16 (2 VALU ops)
static __device__ __forceinline__ u16 f2b(float f) {
  return (u16)((__float_as_uint(f) + 0x8000u) >> 16);
}
static __device__ __forceinline__ u32 pk2(float a, float b) {
  return ((__float_as_uint(a) + 0x8000u) >> 16) |
         ((__float_as_uint(b) + 0x8000u) & 0xffff0000u);
}
// 1-op truncating pack: low16 <- hi16(a), high16 <- hi16(b)  (v_perm_b32)
static __device__ __forceinline__ u32 pk2t(float a, float b) {
  return __builtin_amdgcn_perm(__float_as_uint(b), __float_as_uint(a), 0x07060302u);
}
static __device__ __forceinline__ short8 mk8(u32 a, u32 b, u32 c, u32 d) {
  union { u32 u[4]; short8 s; } t;
  t.u[0] = a; t.u[1] = b; t.u[2] = c; t.u[3] = d;
  return t.s;
}

// ---------------- Phase 0: one-time W -> bf16 (+log2e fold on Wq), biases ----
// whi layout: [3][64 o][64 c] bf16 unpadded; L2-resident for the fused kernel.
__global__ __launch_bounds__(256) void w_prep(
    const float* __restrict__ Wq, const float* __restrict__ bq,
    const float* __restrict__ Wk, const float* __restrict__ bk,
    const float* __restrict__ Wv, const float* __restrict__ bv,
    u16* __restrict__ whi, float* __restrict__ bsc)
{
  const int idx = blockIdx.x * 256 + threadIdx.x;   // grid 48 -> 12288
  const int m = idx >> 12;
  const float* W = (m == 0) ? Wq : (m == 1) ? Wk : Wv;
  const float w = W[idx & 4095] * ((m == 0) ? LOG2E : 1.0f);
  whi[idx] = f2b(w);
  if (blockIdx.x == 0 && threadIdx.x < 192)
    bsc[threadIdx.x] = (threadIdx.x < 64) ? bq[threadIdx.x] * LOG2E
                     : (threadIdx.x < 128) ? bk[threadIdx.x - 64] : bv[threadIdx.x - 128];
}

// ---------------- Fused QKV + flash attention --------------------------------
// grid 512 = 64 bt (XCD pin: blk%8==bt%8) x 8 i-ranges of 128; 8 waves x 16 i.
// NO K/V global round-trip: each block RE-PROJECTS the K/V chunk it needs,
// straight into double-buffered LDS (projection is 4 MFMA-pairs/wave/chunk --
// FLOP-trivial; x is 256KB/bt, XCD-L2-resident, 4x re-read is free).
//   Per 64-j chunk: wave (jt=w&3, ots={2(w>>2),2(w>>2)+1}) computes
//   K[ot][jt], V[ot][jt] tiles from direct-x loads (issued BEFORE the attn
//   phase -> L2 latency hides under it).
//   K written sigma-PERMUTED ([j&32]|((j&4)<<2)|((j&24)>>1)|(j&3)) so the
//   S^T output regs across a stored-tile pair ARE the K=32 PV A-fragment
//   (round-2 trick). V written [c][j], pad 72. ONE barrier per chunk.
// Attention wave body = round-2 proven code with a single 16-i tile
// (qf 8 + O 16 regs -- half the j-split state, no spill).
__global__ __launch_bounds__(512) void fused_kernel(
    const float* __restrict__ x,
    const u16* __restrict__ whi, const float* __restrict__ bsc,
    float* __restrict__ out)
{
  // 40,960B: [K0|V0|K1|V1] = 36,864 (each 64x72 u16); prologue tbuf overlays
  // buf1; epilogue of-buffers (8 x 64x20 f32 = 40,960) overlay everything.
  __shared__ __align__(16) u16 smem[20480];

  const int tid  = threadIdx.x;
  const int wave = tid >> 6;          // 0..7
  const int lane = tid & 63;
  const int l16  = lane & 15;
  const int quad = lane >> 4;

  const int bt  = blockIdx.x & 63;
  const int ih  = blockIdx.x >> 6;    // 0..7
  const int i0w = (ih << 7) + (wave << 4);   // this wave's 16 i rows

  const int jt  = wave & 3;           // proj: j-tile owned by this wave
  const int ot0 = (wave >> 2) << 1;   // proj: o-tiles {ot0, ot0+1}

  const float* xbt = x + (size_t)bt * CC * LL;

  // ---- Q prologue: project this wave's 16 q-rows, transpose via tbuf ----
  short8 qf0, qf1;
  {
    const float* xq = xbt + i0w + l16;
    float qx[16];
    #pragma unroll
    for (int e = 0; e < 8; ++e) {
      qx[e]     = xq[(size_t)(quad * 8 + e) * LL];
      qx[8 + e] = xq[(size_t)(quad * 8 + 32 + e) * LL];
    }
    const short8 qxh0 = mk8(pk2(qx[0], qx[1]), pk2(qx[2], qx[3]),
                            pk2(qx[4], qx[5]), pk2(qx[6], qx[7]));
    const short8 qxh1 = mk8(pk2(qx[8], qx[9]), pk2(qx[10], qx[11]),
                            pk2(qx[12], qx[13]), pk2(qx[14], qx[15]));
    u16* tb = smem + 9216 + wave * 1152;   // overlays buf1 (safe pre-loop)
    #pragma unroll
    for (int ot = 0; ot < 4; ++ot) {
      const int off = ((ot * 16 + l16) << 6) + quad * 8;   // m=0 (Wq)
      const short8 ah0 = *(const short8*)(whi + off);
      const short8 ah1 = *(const short8*)(whi + off + 32);
      floatx4 acc = (floatx4){0.f, 0.f, 0.f, 0.f};
      acc = __builtin_amdgcn_mfma_f32_16x16x32_bf16(ah0, qxh0, acc, 0, 0, 0);
      acc = __builtin_amdgcn_mfma_f32_16x16x32_bf16(ah1, qxh1, acc, 0, 0, 0);
      const float4 bb = *(const float4*)(bsc + ot * 16 + quad * 4);
      uint2 pv;
      pv.x = pk2(acc[0] + bb.x, acc[1] + bb.y);
      pv.y = pk2(acc[2] + bb.z, acc[3] + bb.w);
      *(uint2*)(tb + l16 * 72 + ot * 16 + quad * 4) = pv;
    }
    asm volatile("" ::: "memory");
    qf0 = *(const short8*)(tb + l16 * 72 + quad * 8);
    qf1 = *(const short8*)(tb + l16 * 72 + quad * 8 + 32);
    asm volatile("" ::: "memory");
  }

  floatx4 O[4];
  #pragma unroll
  for (int cf = 0; cf < 4; ++cf)
    O[cf] = (floatx4){0.f, 0.f, 0.f, 0.f};
  float lsA = 0.f, lsB = 0.f;

  const int jloc = jt * 16 + l16;     // proj j within chunk
  const int srow = (jloc & 32) | ((jloc & 4) << 2) | ((jloc & 24) >> 1) | (jloc & 3);

  // proj: K/V tiles for this wave's (jt, ot-pair) from preloaded x regs
  auto proj = [&](const float (&px)[16], u16* Kb, u16* Vb) {
    const short8 xh0 = mk8(pk2(px[0], px[1]), pk2(px[2], px[3]),
                           pk2(px[4], px[5]), pk2(px[6], px[7]));
    const short8 xh1 = mk8(pk2(px[8], px[9]), pk2(px[10], px[11]),
                           pk2(px[12], px[13]), pk2(px[14], px[15]));
    #pragma unroll
    for (int o2 = 0; o2 < 2; ++o2) {
      const int ot = ot0 + o2;
      {   // K tile (m=1), write sigma-permuted rows [j][o]
        const int off = 4096 + ((ot * 16 + l16) << 6) + quad * 8;
        const short8 ah0 = *(const short8*)(whi + off);
        const short8 ah1 = *(const short8*)(whi + off + 32);
        floatx4 acc = (floatx4){0.f, 0.f, 0.f, 0.f};
        acc = __builtin_amdgcn_mfma_f32_16x16x32_bf16(ah0, xh0, acc, 0, 0, 0);
        acc = __builtin_amdgcn_mfma_f32_16x16x32_bf16(ah1, xh1, acc, 0, 0, 0);
        const float4 bb = *(const float4*)(bsc + 64 + ot * 16 + quad * 4);
        uint2 pv;
        pv.x = pk2(acc[0] + bb.x, acc[1] + bb.y);
        pv.y = pk2(acc[2] + bb.z, acc[3] + bb.w);
        *(uint2*)(Kb + srow * 72 + ot * 16 + quad * 4) = pv;
      }
      {   // V tile (m=2), write [c][j]
        const int off = 8192 + ((ot * 16 + l16) << 6) + quad * 8;
        const short8 ah0 = *(const short8*)(whi + off);
        const short8 ah1 = *(const short8*)(whi + off + 32);
        floatx4 acc = (floatx4){0.f, 0.f, 0.f, 0.f};
        acc = __builtin_amdgcn_mfma_f32_16x16x32_bf16(ah0, xh0, acc, 0, 0, 0);
        acc = __builtin_amdgcn_mfma_f32_16x16x32_bf16(ah1, xh1, acc, 0, 0, 0);
        const float4 bb = *(const float4*)(bsc + 128 + ot * 16 + quad * 4);
        #pragma unroll
        for (int r = 0; r < 4; ++r) {
          const float ov = acc[r] + ((const float*)&bb)[r];
          Vb[(ot * 16 + quad * 4 + r) * 72 + jloc] = f2b(ov);
        }
      }
    }
  };

  // ---- chunk 0 projection ----
  {
    float p0[16];
    const float* xp = xbt + jt * 16 + l16;
    #pragma unroll
    for (int e = 0; e < 8; ++e) {
      p0[e]     = xp[(size_t)(quad * 8 + e) * LL];
      p0[8 + e] = xp[(size_t)(quad * 8 + 32 + e) * LL];
    }
    proj(p0, smem, smem + 4608);
  }
  __syncthreads();

  // ---- main loop over 16 j-chunks ----
  for (int t = 0; t < 16; ++t) {
    const u16* Kc = smem + (t & 1) * 9216;
    const u16* Vc = Kc + 4608;

    float px[16];
    if (t < 15) {   // issue next-chunk x loads: latency hides under attn
      const float* xp = xbt + ((t + 1) << 6) + jt * 16 + l16;
      #pragma unroll
      for (int e = 0; e < 8; ++e) {
        px[e]     = xp[(size_t)(quad * 8 + e) * LL];
        px[8 + e] = xp[(size_t)(quad * 8 + 32 + e) * LL];
      }
    }

    // S^T: D[j_stored][i] (sigma rows)
    floatx4 S[4];
    __builtin_amdgcn_s_setprio(1);
    #pragma unroll
    for (int jt2 = 0; jt2 < 4; ++jt2) {
      const u16* ka = Kc + (jt2 * 16 + l16) * 72 + quad * 8;
      const short8 a0 = *(const short8*)(ka);
      const short8 a1 = *(const short8*)(ka + 32);
      floatx4 acc = (floatx4){0.f, 0.f, 0.f, 0.f};
      acc = __builtin_amdgcn_mfma_f32_16x16x32_bf16(a0, qf0, acc, 0, 0, 0);
      acc = __builtin_amdgcn_mfma_f32_16x16x32_bf16(a1, qf1, acc, 0, 0, 0);
      S[jt2] = acc;
    }
    __builtin_amdgcn_s_setprio(0);

    // V fragments early (lgkm hides under exp2)
    short8 v0f[4], v1f[4];
    #pragma unroll
    for (int cf = 0; cf < 4; ++cf) {
      const u16* va = Vc + (cf * 16 + l16) * 72 + quad * 8;
      v0f[cf] = *(const short8*)(va);
      v1f[cf] = *(const short8*)(va + 32);
    }

    uint2 pp[4];
    #pragma unroll
    for (int jt2 = 0; jt2 < 4; ++jt2) {
      const float e0 = __builtin_amdgcn_exp2f(S[jt2][0]);
      const float e1 = __builtin_amdgcn_exp2f(S[jt2][1]);
      const float e2 = __builtin_amdgcn_exp2f(S[jt2][2]);
      const float e3 = __builtin_amdgcn_exp2f(S[jt2][3]);
      lsA += e0 + e1;
      lsB += e2 + e3;
      pp[jt2].x = pk2t(e0, e1);
      pp[jt2].y = pk2t(e2, e3);
    }

    __builtin_amdgcn_s_setprio(1);
    {
      const short8 pa0 = mk8(pp[0].x, pp[0].y, pp[1].x, pp[1].y);
      const short8 pa1 = mk8(pp[2].x, pp[2].y, pp[3].x, pp[3].y);
      #pragma unroll
      for (int cf = 0; cf < 4; ++cf) {
        O[cf] = __builtin_amdgcn_mfma_f32_16x16x32_bf16(pa0, v0f[cf], O[cf], 0, 0, 0);
        O[cf] = __builtin_amdgcn_mfma_f32_16x16x32_bf16(pa1, v1f[cf], O[cf], 0, 0, 0);
      }
    }
    __builtin_amdgcn_s_setprio(0);

    if (t < 15) {
      u16* Kn = smem + ((t + 1) & 1) * 9216;
      proj(px, Kn, Kn + 4608);
    }
    __syncthreads();
  }

  // ---- epilogue: 1/lsum scale + transpose-store (round-2 proven) ----
  float lsum = lsA + lsB;
  lsum += __shfl_xor(lsum, 16, 64);
  lsum += __shfl_xor(lsum, 32, 64);

  float* ofw = (float*)smem + wave * 1280;   // [64 c][20] per wave
  #pragma unroll
  for (int r = 0; r < 4; ++r) {
    const float rl = __builtin_amdgcn_rcpf(__shfl(lsum, quad * 4 + r, 64));
    #pragma unroll
    for (int cf = 0; cf < 4; ++cf)
      O[cf][r] *= rl;
  }
  asm volatile("" ::: "memory");
  #pragma unroll
  for (int cf = 0; cf < 4; ++cf)
    #pragma unroll
    for (int r = 0; r < 4; ++r)
      ofw[(cf * 16 + l16) * 20 + quad * 4 + r] = O[cf][r];
  asm volatile("" ::: "memory");
  {
    float* ob = out + (size_t)bt * CC * LL + i0w;
    #pragma unroll
    for (int rr = 0; rr < 4; ++rr) {
      const int c = rr * 16 + l16;
      float4 val = *(const float4*)(ofw + c * 20 + quad * 4);
      *(float4*)(ob + (size_t)c * LL + quad * 4) = val;
    }
  }
  asm volatile("" ::: "memory");
}

extern "C" void kernel_launch(void* const* d_in, const int* in_sizes, int n_in,
                              void* d_out, int out_size, void* d_ws, size_t ws_size,
                              hipStream_t stream) {
  const float* x  = (const float*)d_in[0];
  const float* Wq = (const float*)d_in[1];
  const float* bq = (const float*)d_in[2];
  const float* Wk = (const float*)d_in[3];
  const float* bk = (const float*)d_in[4];
  const float* Wv = (const float*)d_in[5];
  const float* bv = (const float*)d_in[6];
  float* out = (float*)d_out;

  u16* whi = (u16*)d_ws;                          // 24 KB
  float* bsc = (float*)(whi + 3 * 64 * 64);       // 768 B

  w_prep<<<48, 256, 0, stream>>>(Wq, bq, Wk, bk, Wv, bv, whi, bsc);
  fused_kernel<<<512, 512, 0, stream>>>(x, whi, bsc, out);
}

// Round 10
// 123.094 us; speedup vs baseline: 1.2747x; 1.0489x over previous
//
#include <hip/hip_runtime.h>

#define CC 64
#define LL 1024
#define LOG2E 1.44269504f

typedef unsigned short u16;
typedef unsigned int u32;
typedef __attribute__((ext_vector_type(8))) short short8;
typedef __attribute__((ext_vector_type(4))) float floatx4;

// RN ties-away float->bf16
static __device__ __forceinline__ u16 f2b(float f) {
  return (u16)((__float_as_uint(f) + 0x8000u) >> 16);
}
// 3-op RN pack: low16 <- rn(a), high16 <- rn(b)  (2 adds + v_perm)
static __device__ __forceinline__ u32 pk2r(float a, float b) {
  return __builtin_amdgcn_perm(__float_as_uint(b) + 0x8000u,
                               __float_as_uint(a) + 0x8000u, 0x07060302u);
}
// 1-op truncating pack (used only on exp2 outputs, r2-proven)
static __device__ __forceinline__ u32 pk2t(float a, float b) {
  return __builtin_amdgcn_perm(__float_as_uint(b), __float_as_uint(a), 0x07060302u);
}
static __device__ __forceinline__ short8 mk8(u32 a, u32 b, u32 c, u32 d) {
  union { u32 u[4]; short8 s; } t;
  t.u[0] = a; t.u[1] = b; t.u[2] = c; t.u[3] = d;
  return t.s;
}

// ---------------- Phase 0: x -> bf16 TRANSPOSED + W -> bf16 ------------------
// xhT[bt][l][c] bf16: fused's proj fragment becomes 2 coalesced short8 loads
// (replaces 16 scalar f32 loads + 8 pk2 per wave-chunk). W work (12288 elems)
// spread 12/block; whi [3][64 o][64 c] bf16 unpadded (L2-resident).
__global__ __launch_bounds__(256) void xw_prep(
    const float* __restrict__ x,
    const float* __restrict__ Wq, const float* __restrict__ bq,
    const float* __restrict__ Wk, const float* __restrict__ bk,
    const float* __restrict__ Wv, const float* __restrict__ bv,
    u16* __restrict__ xhT, u16* __restrict__ whi, float* __restrict__ bsc)
{
  __shared__ __align__(16) u16 xh_s[64 * 72];
  const int tid = threadIdx.x;
  const int blk = blockIdx.x;              // 1024 = 64 bt x 16 l-chunks
  const int bt  = blk & 63;
  const int l0  = (blk >> 6) << 6;

  // W convert: 12 elems/block
  if (tid < 12) {
    const int widx = blk * 12 + tid;       // 0..12287
    const int m = widx >> 12;
    const float* W = (m == 0) ? Wq : (m == 1) ? Wk : Wv;
    whi[widx] = f2b(W[widx & 4095] * ((m == 0) ? LOG2E : 1.0f));
  }
  if (blk == 0 && tid < 192)
    bsc[tid] = (tid < 64) ? bq[tid] * LOG2E
             : (tid < 128) ? bk[tid - 64] : bv[tid - 128];

  // stage 64l x 64c tile: read x[c][l] coalesced, LDS holds [l][c]
  const int lx = tid & 63;
  const int cg = (tid >> 6) << 4;
  const float* xp = x + ((size_t)bt * CC + cg) * LL + l0 + lx;
  float v0[16];
  #pragma unroll
  for (int e = 0; e < 16; ++e) v0[e] = xp[(size_t)e * LL];
  #pragma unroll
  for (int e = 0; e < 16; e += 2)
    *(u32*)(xh_s + lx * 72 + cg + e) = pk2r(v0[e], v0[e + 1]);
  __syncthreads();

  // writeback rows [l][c] (128B rows, fully coalesced)
  const int r_st = tid >> 2;
  const int c_st = (tid & 3) << 4;
  u16* gd = xhT + ((size_t)(bt * LL + l0 + r_st)) * CC + c_st;
  uint4 a = *(const uint4*)(xh_s + r_st * 72 + c_st);      // 144B stride: 16B-aligned
  uint4 b = *(const uint4*)(xh_s + r_st * 72 + c_st + 8);
  *(uint4*)(gd) = a;
  *(uint4*)(gd + 8) = b;
}

// ---------------- Fused QKV + flash attention --------------------------------
// grid 512 = 64 bt (XCD pin) x 8 i-ranges; 8 waves x 16 i. Structure = round-9
// (passing) with the projection slimmed:
//  - x fragment: 2 short8 loads from xhT (same regs serve K-proj B-operand AND
//    V-proj A-operand -- identical lane maps).
//  - V^T swap: mfma(x, Wv) gives D lane (j=quad*4+r, c=l16) -> V[c][j] written
//    as ONE uint2/ot (was 4 scalar u16 stores, the main conflict source).
//  - pk2 -> pk2r (3 VALU ops).
// K sigma-store, S/PV, epilogue: unchanged from round 9.
__global__ __launch_bounds__(512) void fused_kernel(
    const u16* __restrict__ xhT,
    const u16* __restrict__ whi, const float* __restrict__ bsc,
    float* __restrict__ out)
{
  __shared__ __align__(16) u16 smem[20480];   // K0|V0|K1|V1 + overlays

  const int tid  = threadIdx.x;
  const int wave = tid >> 6;          // 0..7
  const int lane = tid & 63;
  const int l16  = lane & 15;
  const int quad = lane >> 4;

  const int bt  = blockIdx.x & 63;
  const int ih  = blockIdx.x >> 6;    // 0..7
  const int i0w = (ih << 7) + (wave << 4);

  const int jt  = wave & 3;           // proj: j-tile owned by this wave
  const int ot0 = (wave >> 2) << 1;   // proj: o-tiles {ot0, ot0+1}

  const u16* xbt = xhT + (size_t)bt * LL * CC;

  // ---- Q prologue: project 16 q-rows, transpose via tbuf (overlays buf1) ----
  short8 qf0, qf1;
  {
    const u16* xq = xbt + (size_t)(i0w + l16) * CC + quad * 8;
    const short8 qxh0 = *(const short8*)(xq);
    const short8 qxh1 = *(const short8*)(xq + 32);
    u16* tb = smem + 9216 + wave * 1152;
    #pragma unroll
    for (int ot = 0; ot < 4; ++ot) {
      const int off = ((ot * 16 + l16) << 6) + quad * 8;   // m=0 (Wq)
      const short8 ah0 = *(const short8*)(whi + off);
      const short8 ah1 = *(const short8*)(whi + off + 32);
      floatx4 acc = (floatx4){0.f, 0.f, 0.f, 0.f};
      acc = __builtin_amdgcn_mfma_f32_16x16x32_bf16(ah0, qxh0, acc, 0, 0, 0);
      acc = __builtin_amdgcn_mfma_f32_16x16x32_bf16(ah1, qxh1, acc, 0, 0, 0);
      const float4 bb = *(const float4*)(bsc + ot * 16 + quad * 4);
      uint2 pv;
      pv.x = pk2r(acc[0] + bb.x, acc[1] + bb.y);
      pv.y = pk2r(acc[2] + bb.z, acc[3] + bb.w);
      *(uint2*)(tb + l16 * 72 + ot * 16 + quad * 4) = pv;
    }
    asm volatile("" ::: "memory");
    qf0 = *(const short8*)(tb + l16 * 72 + quad * 8);
    qf1 = *(const short8*)(tb + l16 * 72 + quad * 8 + 32);
    asm volatile("" ::: "memory");
  }

  floatx4 O[4];
  #pragma unroll
  for (int cf = 0; cf < 4; ++cf)
    O[cf] = (floatx4){0.f, 0.f, 0.f, 0.f};
  float lsA = 0.f, lsB = 0.f;

  const int jloc = jt * 16 + l16;
  const int srow = (jloc & 32) | ((jloc & 4) << 2) | ((jloc & 24) >> 1) | (jloc & 3);
  const float bvv = bsc[128 + ot0 * 16 + l16];        // Wv bias, c = ot*16+l16
  const float bvv1 = bsc[128 + (ot0 + 1) * 16 + l16];

  // proj: K (sigma rows) + V^T (swap) tiles for this wave's (jt, ot-pair)
  auto proj = [&](short8 xh0, short8 xh1, u16* Kb, u16* Vb) {
    #pragma unroll
    for (int o2 = 0; o2 < 2; ++o2) {
      const int ot = ot0 + o2;
      const int offK = 4096 + ((ot * 16 + l16) << 6) + quad * 8;
      const int offV = 8192 + ((ot * 16 + l16) << 6) + quad * 8;
      {   // K tile: D lane (o=quad*4+r, j=l16); write sigma-permuted [j][o]
        const short8 ah0 = *(const short8*)(whi + offK);
        const short8 ah1 = *(const short8*)(whi + offK + 32);
        floatx4 acc = (floatx4){0.f, 0.f, 0.f, 0.f};
        acc = __builtin_amdgcn_mfma_f32_16x16x32_bf16(ah0, xh0, acc, 0, 0, 0);
        acc = __builtin_amdgcn_mfma_f32_16x16x32_bf16(ah1, xh1, acc, 0, 0, 0);
        const float4 bb = *(const float4*)(bsc + 64 + ot * 16 + quad * 4);
        uint2 pv;
        pv.x = pk2r(acc[0] + bb.x, acc[1] + bb.y);
        pv.y = pk2r(acc[2] + bb.z, acc[3] + bb.w);
        *(uint2*)(Kb + srow * 72 + ot * 16 + quad * 4) = pv;
      }
      {   // V^T tile: mfma(x, Wv) -> D lane (j=quad*4+r, c=l16); write [c][j]
        const short8 av0 = *(const short8*)(whi + offV);
        const short8 av1 = *(const short8*)(whi + offV + 32);
        floatx4 acc = (floatx4){0.f, 0.f, 0.f, 0.f};
        acc = __builtin_amdgcn_mfma_f32_16x16x32_bf16(xh0, av0, acc, 0, 0, 0);
        acc = __builtin_amdgcn_mfma_f32_16x16x32_bf16(xh1, av1, acc, 0, 0, 0);
        const float bv = o2 ? bvv1 : bvv;
        uint2 pv;
        pv.x = pk2r(acc[0] + bv, acc[1] + bv);
        pv.y = pk2r(acc[2] + bv, acc[3] + bv);
        *(uint2*)(Vb + (ot * 16 + l16) * 72 + jt * 16 + quad * 4) = pv;
      }
    }
  };

  // ---- chunk 0 projection ----
  {
    const u16* xp = xbt + (size_t)jloc * CC + quad * 8;
    const short8 x0 = *(const short8*)(xp);
    const short8 x1 = *(const short8*)(xp + 32);
    proj(x0, x1, smem, smem + 4608);
  }
  __syncthreads();

  // ---- main loop over 16 j-chunks ----
  for (int t = 0; t < 16; ++t) {
    const u16* Kc = smem + (t & 1) * 9216;
    const u16* Vc = Kc + 4608;

    short8 pxh0, pxh1;
    if (t < 15) {   // issue next-chunk x loads; L2 latency hides under attn
      const u16* xp = xbt + (size_t)(((t + 1) << 6) + jloc) * CC + quad * 8;
      pxh0 = *(const short8*)(xp);
      pxh1 = *(const short8*)(xp + 32);
    }

    // S^T: D[j_stored][i] (sigma rows)
    floatx4 S[4];
    __builtin_amdgcn_s_setprio(1);
    #pragma unroll
    for (int jt2 = 0; jt2 < 4; ++jt2) {
      const u16* ka = Kc + (jt2 * 16 + l16) * 72 + quad * 8;
      const short8 a0 = *(const short8*)(ka);
      const short8 a1 = *(const short8*)(ka + 32);
      floatx4 acc = (floatx4){0.f, 0.f, 0.f, 0.f};
      acc = __builtin_amdgcn_mfma_f32_16x16x32_bf16(a0, qf0, acc, 0, 0, 0);
      acc = __builtin_amdgcn_mfma_f32_16x16x32_bf16(a1, qf1, acc, 0, 0, 0);
      S[jt2] = acc;
    }
    __builtin_amdgcn_s_setprio(0);

    // V fragments early (lgkm hides under exp2)
    short8 v0f[4], v1f[4];
    #pragma unroll
    for (int cf = 0; cf < 4; ++cf) {
      const u16* va = Vc + (cf * 16 + l16) * 72 + quad * 8;
      v0f[cf] = *(const short8*)(va);
      v1f[cf] = *(const short8*)(va + 32);
    }

    uint2 pp[4];
    #pragma unroll
    for (int jt2 = 0; jt2 < 4; ++jt2) {
      const float e0 = __builtin_amdgcn_exp2f(S[jt2][0]);
      const float e1 = __builtin_amdgcn_exp2f(S[jt2][1]);
      const float e2 = __builtin_amdgcn_exp2f(S[jt2][2]);
      const float e3 = __builtin_amdgcn_exp2f(S[jt2][3]);
      lsA += e0 + e1;
      lsB += e2 + e3;
      pp[jt2].x = pk2t(e0, e1);
      pp[jt2].y = pk2t(e2, e3);
    }

    __builtin_amdgcn_s_setprio(1);
    {
      const short8 pa0 = mk8(pp[0].x, pp[0].y, pp[1].x, pp[1].y);
      const short8 pa1 = mk8(pp[2].x, pp[2].y, pp[3].x, pp[3].y);
      #pragma unroll
      for (int cf = 0; cf < 4; ++cf) {
        O[cf] = __builtin_amdgcn_mfma_f32_16x16x32_bf16(pa0, v0f[cf], O[cf], 0, 0, 0);
        O[cf] = __builtin_amdgcn_mfma_f32_16x16x32_bf16(pa1, v1f[cf], O[cf], 0, 0, 0);
      }
    }
    __builtin_amdgcn_s_setprio(0);

    if (t < 15) {
      u16* Kn = smem + ((t + 1) & 1) * 9216;
      proj(pxh0, pxh1, Kn, Kn + 4608);
    }
    __syncthreads();
  }

  // ---- epilogue: 1/lsum scale + transpose-store (round-2 proven) ----
  float lsum = lsA + lsB;
  lsum += __shfl_xor(lsum, 16, 64);
  lsum += __shfl_xor(lsum, 32, 64);

  float* ofw = (float*)smem + wave * 1280;   // [64 c][20] per wave
  #pragma unroll
  for (int r = 0; r < 4; ++r) {
    const float rl = __builtin_amdgcn_rcpf(__shfl(lsum, quad * 4 + r, 64));
    #pragma unroll
    for (int cf = 0; cf < 4; ++cf)
      O[cf][r] *= rl;
  }
  asm volatile("" ::: "memory");
  #pragma unroll
  for (int cf = 0; cf < 4; ++cf)
    #pragma unroll
    for (int r = 0; r < 4; ++r)
      ofw[(cf * 16 + l16) * 20 + quad * 4 + r] = O[cf][r];
  asm volatile("" ::: "memory");
  {
    float* ob = out + (size_t)bt * CC * LL + i0w;
    #pragma unroll
    for (int rr = 0; rr < 4; ++rr) {
      const int c = rr * 16 + l16;
      float4 val = *(const float4*)(ofw + c * 20 + quad * 4);
      *(float4*)(ob + (size_t)c * LL + quad * 4) = val;
    }
  }
  asm volatile("" ::: "memory");
}

extern "C" void kernel_launch(void* const* d_in, const int* in_sizes, int n_in,
                              void* d_out, int out_size, void* d_ws, size_t ws_size,
                              hipStream_t stream) {
  const float* x  = (const float*)d_in[0];
  const float* Wq = (const float*)d_in[1];
  const float* bq = (const float*)d_in[2];
  const float* Wk = (const float*)d_in[3];
  const float* bk = (const float*)d_in[4];
  const float* Wv = (const float*)d_in[5];
  const float* bv = (const float*)d_in[6];
  float* out = (float*)d_out;

  u16* xhT = (u16*)d_ws;                          // 8 MB
  u16* whi = xhT + (size_t)64 * LL * CC;          // 24 KB
  float* bsc = (float*)(whi + 3 * 64 * 64);       // 768 B

  xw_prep<<<1024, 256, 0, stream>>>(x, Wq, bq, Wk, bk, Wv, bv, xhT, whi, bsc);
  fused_kernel<<<512, 512, 0, stream>>>(xhT, whi, bsc, out);
}